// Round 4
// baseline (93.035 us; speedup 1.0000x reference)
//
#include <hip/hip_runtime.h>
#include <hip/hip_fp16.h>
#include <math.h>

#define BB 2
#define LL 2048
#define HH 128
#define NN 64
#define EPSF 1e-12f
#define T_A 13.8f       /* |z| > 1e-6  -> gate == 1 to <1e-6 */
#define T_C 34.5f       /* |z| < 1e-15 -> contribution negligible */
#define ROWPH 70        /* ushort pitch: row base dword 35*t -> bank 3t%32, conflict-free */

__device__ __forceinline__ float bcast_lane(float v, int idx) {
  return __int_as_float(__builtin_amdgcn_readlane(__float_as_int(v), idx));
}

// ---------------- k0p: per-(h,n) params + per-h regime limits ----------------
extern "C" __global__ __launch_bounds__(256)
void s4d_k0p(const float* __restrict__ lar, const float* __restrict__ aim,
             const float* __restrict__ Bp, const float* __restrict__ ldt,
             const float* __restrict__ Cp,
             float4* __restrict__ params4, float2* __restrict__ paramsB,
             int2* __restrict__ limits)
{
  int lane = threadIdx.x & 63;
  int h = blockIdx.x * 4 + (threadIdx.x >> 6);
  float dt  = expf(ldt[0]);
  float lre = -expf(lar[h*NN + lane]);
  float w   = aim[h*NN + lane];
  float ar = lre * dt, ai = w * dt;
  float er = expf(ar);
  float s, c; sincosf(ai, &s, &c);
  float are = er * c, aie = er * s;
  float em1r = are - 1.0f, em1i = aie;
  float il2  = 1.0f / (lre*lre + w*w);
  float qr = (em1r*lre + em1i*w) * il2;
  float qi = (em1i*lre - em1r*w) * il2;
  float br = Bp[(h*NN+lane)*2+0], bi = Bp[(h*NN+lane)*2+1];
  float dbr = br*qr - bi*qi, dbi = br*qi + bi*qr;
  float cr = Cp[lane*2+0], ci = Cp[lane*2+1];
  float kr = cr*dbr - ci*dbi;
  float ki = cr*dbi + ci*dbr;
  params4[h*NN+lane] = make_float4(are, aie, kr, ki);
  paramsB[h*NN+lane] = make_float2(ar, ai);
  float arn = -ar, mx = arn, mn = arn;
  #pragma unroll
  for (int m = 32; m >= 1; m >>= 1) {
    mx = fmaxf(mx, __shfl_xor(mx, m));
    mn = fminf(mn, __shfl_xor(mn, m));
  }
  if (lane == 0) limits[h] = make_int2((int)(T_A / mx), (int)(T_C / mn) + 1);
}

// ---------------- k0t: transpose u[b][t][h] -> uT[b][h][t] ----------------
extern "C" __global__ __launch_bounds__(256)
void s4d_k0t(const float* __restrict__ u, float* __restrict__ uT)
{
  __shared__ float tile[64][65];
  int bidx = blockIdx.x;            // b*(L/64)*(H/64): hb fastest
  int hb = bidx & ((HH/64)-1);
  int tb = (bidx >> 1) & ((LL/64)-1);
  int b  = bidx >> 6;
  int tx = threadIdx.x & 63;
  int ty = threadIdx.x >> 6;
  const float* up = u + ((size_t)b*LL + (size_t)tb*64)*HH + hb*64;
  #pragma unroll
  for (int r = 0; r < 64; r += 4)
    tile[r + ty][tx] = up[(size_t)(r + ty)*HH + tx];
  __syncthreads();
  float* utp = uT + ((size_t)b*HH + (size_t)hb*64)*LL + tb*64;
  #pragma unroll
  for (int r = 0; r < 64; r += 4)
    utp[(size_t)(r + ty)*LL + tx] = tile[tx][r + ty];
}

// ---------------- k1: per-chunk local end states ----------------
template<int LCH>
__global__ __launch_bounds__(256, 8)
void s4d_k1(const float* __restrict__ uT, const float4* __restrict__ params4,
            const float2* __restrict__ paramsB, const int2* __restrict__ limits,
            float2* __restrict__ states)
{
  constexpr int NCHT = LL / LCH;
  int lane = threadIdx.x & 63;
  int wid  = blockIdx.x * 4 + (threadIdx.x >> 6);
  int c = wid % NCHT;
  int h = (wid / NCHT) & (HH-1);
  int b = wid / (NCHT * HH);

  float4 P  = params4[h*NN + lane];      // are, aie, kr, ki
  float2 pb = paramsB[h*NN + lane];      // ar, ai
  int2  lim = limits[h];
  float are = P.x, aie = P.y, kr = P.z, ki = P.w;
  float ar = pb.x, ai = pb.y;

  int t0 = c * LCH, t1 = t0 + LCH;
  size_t sidx = (((size_t)b*HH + h)*NCHT + c)*NN + lane;
  if (t0 >= lim.y) { states[sidx] = make_float2(0.f, 0.f); return; }

  int e1 = min(t1, max(t0, lim.x + 1));
  int e2 = min(t1, max(e1, lim.y));

  const float* uTrow = uT + ((size_t)b*HH + h)*LL;
  float ureg = uTrow[min(t0 + lane, LL-1)];
  float pr = 0.f, pi = 0.f;

  #pragma unroll 4
  for (int t = t0; t < e1; ++t) {            // regime A: gate == 1
    float uv = bcast_lane(ureg, t - t0);
    float prn = fmaf(are, pr, fmaf(-aie, pi, uv * kr));
    float pin = fmaf(aie, pr, fmaf( are, pi, uv * ki));
    pr = prn; pi = pin;
  }
  if (e2 > e1) {                             // regime B: full gate
    float rho = expf(ar * (float)e1);
    float s, cth; sincosf(ai * (float)e1, &s, &cth);
    float zr = rho * cth, zi = rho * s;
    for (int t = e1; t < e2; ++t) {
      float uv  = bcast_lane(ureg, t - t0);
      float dr  = zr + EPSF;
      float den = fmaf(dr, dr, zi*zi);
      float inv = 1.0f / den;
      float gr  = fmaf(zr, dr, zi*zi) * inv;
      float gi  = (zi*dr - zr*zi) * inv;
      float kgr = kr*gr - ki*gi, kgi = kr*gi + ki*gr;
      float prn = fmaf(are, pr, fmaf(-aie, pi, uv * kgr));
      float pin = fmaf(aie, pr, fmaf( are, pi, uv * kgi));
      pr = prn; pi = pin;
      float zrn = zr*are - zi*aie, zin = zr*aie + zi*are;
      zr = zrn; zi = zin;
    }
  }
  int dC = t1 - e2;                          // regime C: pure decay
  if (dC > 0) {
    float rr = expf(ar * (float)dC);
    float s, cth; sincosf(ai * (float)dC, &s, &cth);
    float wr2 = rr * cth, wi2 = rr * s;
    float prn = pr*wr2 - pi*wi2;
    float pin = pr*wi2 + pi*wr2;
    pr = prn; pi = pin;
  }
  states[sidx] = make_float2(pr, pi);
}

// ---------------- k2: exclusive scan of chunk carries ----------------
template<int LCH>
__global__ __launch_bounds__(64)
void s4d_k2(const float2* __restrict__ paramsB, float2* __restrict__ states)
{
  constexpr int NCHT = LL / LCH;
  int tid = blockIdx.x * 64 + threadIdx.x;   // (b,h,n)
  int n = tid & 63;
  int h = (tid >> 6) & (HH-1);
  int b = tid >> 13;
  float2 pb = paramsB[h*NN + n];
  float rr  = expf(pb.x * (float)LCH);
  float s, c; sincosf(pb.y * (float)LCH, &s, &c);
  float Ar = rr*c, Ai = rr*s;                 // exp(dA*LCH)
  float xr = 0.f, xi = 0.f;
  size_t base = ((size_t)b*HH + h)*NCHT*NN + n;
  #pragma unroll 8
  for (int cc = 0; cc < NCHT; ++cc) {
    size_t idx = base + (size_t)cc*NN;
    float2 tmp = states[idx];
    states[idx] = make_float2(xr, xi);        // exclusive carry, in-place
    float xrn = fmaf(Ar, xr, fmaf(-Ai, xi, tmp.x));
    float xin = fmaf(Ai, xr, fmaf( Ar, xi, tmp.y));
    xr = xrn; xi = xin;
  }
}

// ---------------- k3: full scan from carries + y reduction ----------------
template<int LCH, int WPB>
__global__ __launch_bounds__(WPB*64, 8)
void s4d_k3(const float* __restrict__ uT, const float4* __restrict__ params4,
            const float2* __restrict__ paramsB, const int2* __restrict__ limits,
            const float* __restrict__ Dp,
            const float2* __restrict__ states, float* __restrict__ out)
{
  constexpr int NCHT = LL / LCH;
  __shared__ ushort lds[WPB * LCH * ROWPH];
  int lane = threadIdx.x & 63;
  int wv   = threadIdx.x >> 6;
  int wid  = blockIdx.x * WPB + wv;
  int c = wid % NCHT;
  int h = (wid / NCHT) & (HH-1);
  int b = wid / (NCHT * HH);
  ushort* myl = lds + wv * (LCH * ROWPH);

  int t0 = c * LCH, t1 = t0 + LCH;
  size_t sidx = (((size_t)b*HH + h)*NCHT + c)*NN + lane;
  float2 cin = states[sidx];                 // issue early
  float4 P  = params4[h*NN + lane];
  float2 pb = paramsB[h*NN + lane];
  int2  lim = limits[h];
  const float* uTrow = uT + ((size_t)b*HH + h)*LL;
  float ureg = uTrow[min(t0 + lane, LL-1)];
  float Dh = Dp[h];
  float are = P.x, aie = P.y, kr = P.z, ki = P.w;
  float ar = pb.x, ai = pb.y;

  if (t0 >= lim.y) {                         // dead tail: y ~ 0
    if (lane < LCH) out[(size_t)b*LL*HH + (size_t)(t0+lane)*HH + h] = ureg * Dh;
    return;
  }

  int e1 = min(t1, max(t0, lim.x + 1));
  int e2 = min(t1, max(e1, lim.y));

  float pr = cin.x, pi = cin.y;

  #pragma unroll 4
  for (int t = t0; t < e1; ++t) {            // regime A
    float uv = bcast_lane(ureg, t - t0);
    float prn = fmaf(are, pr, fmaf(-aie, pi, uv * kr));
    float pin = fmaf(aie, pr, fmaf( are, pi, uv * ki));
    pr = prn; pi = pin;
    myl[(t - t0) * ROWPH + lane] = __half_as_ushort(__float2half(pr));
  }
  if (e2 > e1) {                             // regime B
    float rho = expf(ar * (float)e1);
    float s, cth; sincosf(ai * (float)e1, &s, &cth);
    float zr = rho * cth, zi = rho * s;
    for (int t = e1; t < e2; ++t) {
      float uv  = bcast_lane(ureg, t - t0);
      float dr  = zr + EPSF;
      float den = fmaf(dr, dr, zi*zi);
      float inv = 1.0f / den;
      float gr  = fmaf(zr, dr, zi*zi) * inv;
      float gi  = (zi*dr - zr*zi) * inv;
      float kgr = kr*gr - ki*gi, kgi = kr*gi + ki*gr;
      float prn = fmaf(are, pr, fmaf(-aie, pi, uv * kgr));
      float pin = fmaf(aie, pr, fmaf( are, pi, uv * kgi));
      pr = prn; pi = pin;
      float zrn = zr*are - zi*aie, zin = zr*aie + zi*are;
      zr = zrn; zi = zin;
      myl[(t - t0) * ROWPH + lane] = __half_as_ushort(__float2half(pr));
    }
  }
  #pragma unroll 4
  for (int t = e2; t < t1; ++t) {            // regime C: pure decay, still emit y
    float prn = fmaf(are, pr, -aie*pi);
    float pin = fmaf(aie, pr,  are*pi);
    pr = prn; pi = pin;
    myl[(t - t0) * ROWPH + lane] = __half_as_ushort(__float2half(pr));
  }

  __builtin_amdgcn_s_waitcnt(0);             // own-wave LDS writes done

  if constexpr (LCH == 32) {
    int m = lane & 31, hf = lane >> 5;       // lane m+32hf sums n in [32hf, 32hf+32)
    const ushort* rowp = myl + m * ROWPH + hf * 32;
    float s = 0.f;
    #pragma unroll
    for (int j = 0; j < 16; ++j) {
      unsigned int v = *reinterpret_cast<const unsigned int*>(rowp + 2*j);
      float2 f = __half22float2(*reinterpret_cast<const __half2*>(&v));
      s += f.x + f.y;
    }
    s += __shfl_xor(s, 32);
    if (lane < 32)
      out[(size_t)b*LL*HH + (size_t)(t0+m)*HH + h] = s + ureg * Dh;
  } else {
    const ushort* rowp = myl + lane * ROWPH;
    float s = 0.f;
    #pragma unroll
    for (int j = 0; j < 32; ++j) {
      unsigned int v = *reinterpret_cast<const unsigned int*>(rowp + 2*j);
      float2 f = __half22float2(*reinterpret_cast<const __half2*>(&v));
      s += f.x + f.y;
    }
    out[(size_t)b*LL*HH + (size_t)(t0+lane)*HH + h] = s + ureg * Dh;
  }
}

extern "C" void kernel_launch(void* const* d_in, const int* in_sizes, int n_in,
                              void* d_out, int out_size, void* d_ws, size_t ws_size,
                              hipStream_t stream)
{
  const float* u   = (const float*)d_in[0];
  const float* lar = (const float*)d_in[1];
  const float* aim = (const float*)d_in[2];
  const float* Bp  = (const float*)d_in[3];
  const float* ldt = (const float*)d_in[4];
  const float* Cp  = (const float*)d_in[5];
  const float* Dp  = (const float*)d_in[6];
  float* out = (float*)d_out;

  auto alignup = [](size_t x) { return (x + 255) & ~(size_t)255; };
  size_t sz_states32 = (size_t)BB*HH*(LL/32)*NN*sizeof(float2);   // 8 MB
  size_t sz_states64 = (size_t)BB*HH*(LL/64)*NN*sizeof(float2);   // 4 MB
  size_t sz_p4 = (size_t)HH*NN*sizeof(float4);
  size_t sz_pb = (size_t)HH*NN*sizeof(float2);
  size_t sz_lim = (size_t)HH*sizeof(int2);
  size_t sz_uT = (size_t)BB*HH*LL*sizeof(float);

  size_t need32 = alignup(sz_states32) + alignup(sz_p4) + alignup(sz_pb)
                + alignup(sz_lim) + alignup(sz_uT);
  bool use32 = ws_size >= need32;
  size_t sz_states = use32 ? sz_states32 : sz_states64;

  char* wp = (char*)d_ws;
  float2* states  = (float2*)wp;            wp += alignup(sz_states);
  float4* params4 = (float4*)wp;            wp += alignup(sz_p4);
  float2* paramsB = (float2*)wp;            wp += alignup(sz_pb);
  int2*   limits  = (int2*)wp;              wp += alignup(sz_lim);
  float*  uT      = (float*)wp;

  s4d_k0p<<<dim3(HH/4), dim3(256), 0, stream>>>(lar, aim, Bp, ldt, Cp, params4, paramsB, limits);
  s4d_k0t<<<dim3(BB*(LL/64)*(HH/64)), dim3(256), 0, stream>>>(u, uT);

  if (use32) {
    constexpr int LCH = 32, NCHT = LL/LCH;
    s4d_k1<LCH><<<dim3(BB*HH*NCHT/4), dim3(256), 0, stream>>>(uT, params4, paramsB, limits, states);
    s4d_k2<LCH><<<dim3(BB*HH*NN/64), dim3(64), 0, stream>>>(paramsB, states);
    s4d_k3<LCH,4><<<dim3(BB*HH*NCHT/4), dim3(256), 0, stream>>>(uT, params4, paramsB, limits, Dp, states, out);
  } else {
    constexpr int LCH = 64, NCHT = LL/LCH;
    s4d_k1<LCH><<<dim3(BB*HH*NCHT/4), dim3(256), 0, stream>>>(uT, params4, paramsB, limits, states);
    s4d_k2<LCH><<<dim3(BB*HH*NN/64), dim3(64), 0, stream>>>(paramsB, states);
    s4d_k3<LCH,2><<<dim3(BB*HH*NCHT/2), dim3(128), 0, stream>>>(uT, params4, paramsB, limits, Dp, states, out);
  }
}